// Round 1
// baseline (104.318 us; speedup 1.0000x reference)
//
#include <hip/hip_runtime.h>

#define B_ 64
#define T_ 1024
#define J_ 52

// One 64-lane wave per (b,t) chain; lane j owns joint j (j < 52).
// Composed transform kept as 9 rotation floats + 3 translation floats per lane.
// Parent composition resolved by wave-level relaxation using dynamic __shfl.
__global__ __launch_bounds__(256) void ForwardKinematics_38543036514646_kernel(
    const float* __restrict__ rotation,   // (B,T,J,3,3)
    const float* __restrict__ position,   // (B,T,3)
    const float* __restrict__ offsets,    // (B,J,3)
    const int*   __restrict__ parents,    // (J,)
    float* __restrict__ out_pos,          // (B,T,J,3)
    float* __restrict__ out_comp)         // (B,T,J,4,4)
{
    const int lane = threadIdx.x & 63;
    const int waveInBlock = threadIdx.x >> 6;
    const long long bt = (long long)blockIdx.x * 4 + waveInBlock;  // [0, B*T)
    const int b = (int)(bt >> 10);   // T = 1024

    const bool active = lane < J_;
    int par = 0;
    if (active && lane > 0) par = parents[lane];   // guaranteed < lane

    float a0,a1,a2,a3,a4,a5,a6,a7,a8;   // local rotation, becomes composed R
    float t0,t1,t2;                     // local translation, becomes composed t
    if (active) {
        const float* rp = rotation + ((bt * J_) + lane) * 9;
        a0 = rp[0]; a1 = rp[1]; a2 = rp[2];
        a3 = rp[3]; a4 = rp[4]; a5 = rp[5];
        a6 = rp[6]; a7 = rp[7]; a8 = rp[8];
        if (lane == 0) {
            const float* pp = position + bt * 3;
            t0 = pp[0]; t1 = pp[1]; t2 = pp[2];
        } else {
            const float* op = offsets + ((long long)b * J_ + lane) * 3;
            t0 = op[0]; t1 = op[1]; t2 = op[2];
        }
    } else {
        a0=a1=a2=a3=a4=a5=a6=a7=a8=0.f; t0=t1=t2=0.f;
    }

    bool done = (lane == 0) || !active;   // root is already final

    #pragma unroll 1
    for (int iter = 0; iter < J_; ++iter) {
        if (__all(done ? 1 : 0)) break;                    // uniform exit
        int   pd = __shfl(done ? 1 : 0, par);
        float p0 = __shfl(a0, par), p1 = __shfl(a1, par), p2 = __shfl(a2, par);
        float p3 = __shfl(a3, par), p4 = __shfl(a4, par), p5 = __shfl(a5, par);
        float p6 = __shfl(a6, par), p7 = __shfl(a7, par), p8 = __shfl(a8, par);
        float q0 = __shfl(t0, par), q1 = __shfl(t1, par), q2 = __shfl(t2, par);
        if (!done && pd) {
            // C = Cp.R @ R  (row-major 3x3)
            float n0 = p0*a0 + p1*a3 + p2*a6;
            float n1 = p0*a1 + p1*a4 + p2*a7;
            float n2 = p0*a2 + p1*a5 + p2*a8;
            float n3 = p3*a0 + p4*a3 + p5*a6;
            float n4 = p3*a1 + p4*a4 + p5*a7;
            float n5 = p3*a2 + p4*a5 + p5*a8;
            float n6 = p6*a0 + p7*a3 + p8*a6;
            float n7 = p6*a1 + p7*a4 + p8*a7;
            float n8 = p6*a2 + p7*a5 + p8*a8;
            // t = Cp.R @ t + Cp.t
            float m0 = p0*t0 + p1*t1 + p2*t2 + q0;
            float m1 = p3*t0 + p4*t1 + p5*t2 + q1;
            float m2 = p6*t0 + p7*t1 + p8*t2 + q2;
            a0=n0; a1=n1; a2=n2; a3=n3; a4=n4; a5=n5; a6=n6; a7=n7; a8=n8;
            t0=m0; t1=m1; t2=m2;
            done = true;
        }
    }

    if (active) {
        // composed (B,T,J,4,4): 64B-aligned, 4x float4 per lane
        float4* oc = (float4*)(out_comp + ((bt * J_) + lane) * 16);
        oc[0] = make_float4(a0, a1, a2, t0);
        oc[1] = make_float4(a3, a4, a5, t1);
        oc[2] = make_float4(a6, a7, a8, t2);
        oc[3] = make_float4(0.f, 0.f, 0.f, 1.f);
        // positions (B,T,J,3)
        float* op = out_pos + ((bt * J_) + lane) * 3;
        op[0] = t0; op[1] = t1; op[2] = t2;
    }
}

extern "C" void kernel_launch(void* const* d_in, const int* in_sizes, int n_in,
                              void* d_out, int out_size, void* d_ws, size_t ws_size,
                              hipStream_t stream) {
    const float* rotation = (const float*)d_in[0];
    const float* position = (const float*)d_in[1];
    const float* offsets  = (const float*)d_in[2];
    const int*   parents  = (const int*)d_in[3];

    float* out_pos  = (float*)d_out;                                  // (B,T,J,3)
    float* out_comp = (float*)d_out + (size_t)B_ * T_ * J_ * 3;       // (B,T,J,4,4)

    const int waves = B_ * T_;            // 65536 chains
    dim3 block(256);                      // 4 waves per block
    dim3 grid(waves / 4);                 // 16384 blocks
    hipLaunchKernelGGL(ForwardKinematics_38543036514646_kernel, grid, block, 0, stream,
                       rotation, position, offsets, parents, out_pos, out_comp);
}

// Round 2
// 99.105 us; speedup vs baseline: 1.0526x; 1.0526x over previous
//
#include <hip/hip_runtime.h>

#define B_ 64
#define T_ 1024
#define J_ 52
#define CH_PER_BLK 4
#define ROTF (J_ * 9)               // 468 floats per chain
#define LDSF (CH_PER_BLK * ROTF)    // 1872 floats = 7488 B
#define POSF (J_ * 3)               // 156 floats per chain

// One 64-lane wave per (b,t) chain; lane j owns joint j.
// Composition via pointer-jumping (path doubling): log2(depth) iterations.
__global__ __launch_bounds__(256) void ForwardKinematics_38543036514646_kernel(
    const float* __restrict__ rotation,   // (B,T,J,3,3)
    const float* __restrict__ position,   // (B,T,3)
    const float* __restrict__ offsets,    // (B,J,3)
    const int*   __restrict__ parents,    // (J,)
    float* __restrict__ out_pos,          // (B,T,J,3)
    float* __restrict__ out_comp)         // (B,T,J,4,4)
{
    __shared__ float lds[LDSF];

    const int tid  = threadIdx.x;
    const int lane = tid & 63;
    const int wv   = tid >> 6;
    const long long bt0 = (long long)blockIdx.x * CH_PER_BLK;
    const long long bt  = bt0 + wv;
    const int b = (int)(bt >> 10);   // T = 1024

    // ---- stage 4 chains of rotations into LDS, fully coalesced float4 ----
    {
        const float4* src = (const float4*)(rotation + bt0 * ROTF);
        float4* dst = (float4*)lds;
        #pragma unroll
        for (int i = tid; i < LDSF / 4; i += 256) dst[i] = src[i];
    }
    __syncthreads();

    const bool active = lane < J_;
    int  par = lane;     // self => acts as terminator
    bool fin = true;     // root & inactive lanes are final from the start
    if (active && lane > 0) { par = parents[lane]; fin = false; }

    float a0,a1,a2,a3,a4,a5,a6,a7,a8;   // running rotation product
    float t0,t1,t2;                     // running translation
    a0=a1=a2=a3=a4=a5=a6=a7=a8=0.f; t0=t1=t2=0.f;
    if (active) {
        const float* rp = lds + wv * ROTF + lane * 9;   // stride 9 dwords: 9⊥32, conflict-free
        a0 = rp[0]; a1 = rp[1]; a2 = rp[2];
        a3 = rp[3]; a4 = rp[4]; a5 = rp[5];
        a6 = rp[6]; a7 = rp[7]; a8 = rp[8];
        if (lane == 0) {
            const float* pp = position + bt * 3;
            t0 = pp[0]; t1 = pp[1]; t2 = pp[2];
        } else {
            const float* op = offsets + ((long long)b * J_ + lane) * 3;
            t0 = op[0]; t1 = op[1]; t2 = op[2];
        }
    }
    __syncthreads();   // all LDS reads done; buffer reused for positions below

    // state packs {fin, par} so both jump in one shuffle
    int state = par | (fin ? 0x100 : 0);

    // Pointer jumping: M spans (anc, j]; compose with anc's span, jump anc.
    // Depth <= 51 => 6 iterations always suffice; break earlier when all final.
    #pragma unroll 1
    for (int it = 0; it < 6; ++it) {
        if (__all(fin ? 1 : 0)) break;
        int   ps = __shfl(state, par);
        float p0 = __shfl(a0, par), p1 = __shfl(a1, par), p2 = __shfl(a2, par);
        float p3 = __shfl(a3, par), p4 = __shfl(a4, par), p5 = __shfl(a5, par);
        float p6 = __shfl(a6, par), p7 = __shfl(a7, par), p8 = __shfl(a8, par);
        float q0 = __shfl(t0, par), q1 = __shfl(t1, par), q2 = __shfl(t2, par);
        if (!fin) {
            float n0 = p0*a0 + p1*a3 + p2*a6;
            float n1 = p0*a1 + p1*a4 + p2*a7;
            float n2 = p0*a2 + p1*a5 + p2*a8;
            float n3 = p3*a0 + p4*a3 + p5*a6;
            float n4 = p3*a1 + p4*a4 + p5*a7;
            float n5 = p3*a2 + p4*a5 + p5*a8;
            float n6 = p6*a0 + p7*a3 + p8*a6;
            float n7 = p6*a1 + p7*a4 + p8*a7;
            float n8 = p6*a2 + p7*a5 + p8*a8;
            float m0 = p0*t0 + p1*t1 + p2*t2 + q0;
            float m1 = p3*t0 + p4*t1 + p5*t2 + q1;
            float m2 = p6*t0 + p7*t1 + p8*t2 + q2;
            a0=n0; a1=n1; a2=n2; a3=n3; a4=n4; a5=n5; a6=n6; a7=n7; a8=n8;
            t0=m0; t1=m1; t2=m2;
            state = ps;
            par   = ps & 0xff;
            fin   = (ps & 0x100) != 0;
        }
    }

    // ---- composed: 4x float4 per lane, contiguous per wave ----
    if (active) {
        float4* oc = (float4*)(out_comp + ((bt * J_) + lane) * 16);
        oc[0] = make_float4(a0, a1, a2, t0);
        oc[1] = make_float4(a3, a4, a5, t1);
        oc[2] = make_float4(a6, a7, a8, t2);
        oc[3] = make_float4(0.f, 0.f, 0.f, 1.f);
        // positions -> LDS (stride 3 dwords: 3⊥32, conflict-free)
        float* lp = lds + wv * POSF + lane * 3;
        lp[0] = t0; lp[1] = t1; lp[2] = t2;
    }
    __syncthreads();

    // ---- positions: coalesced float4 store (624 floats / block) ----
    {
        float4* pd = (float4*)(out_pos + bt0 * POSF);
        const float4* ps4 = (const float4*)lds;
        #pragma unroll
        for (int i = tid; i < (CH_PER_BLK * POSF) / 4; i += 256) pd[i] = ps4[i];
    }
}

extern "C" void kernel_launch(void* const* d_in, const int* in_sizes, int n_in,
                              void* d_out, int out_size, void* d_ws, size_t ws_size,
                              hipStream_t stream) {
    const float* rotation = (const float*)d_in[0];
    const float* position = (const float*)d_in[1];
    const float* offsets  = (const float*)d_in[2];
    const int*   parents  = (const int*)d_in[3];

    float* out_pos  = (float*)d_out;                                  // (B,T,J,3)
    float* out_comp = (float*)d_out + (size_t)B_ * T_ * J_ * 3;       // (B,T,J,4,4)

    dim3 block(256);                        // 4 waves = 4 chains per block
    dim3 grid((B_ * T_) / CH_PER_BLK);      // 16384 blocks
    hipLaunchKernelGGL(ForwardKinematics_38543036514646_kernel, grid, block, 0, stream,
                       rotation, position, offsets, parents, out_pos, out_comp);
}

// Round 3
// 75.260 us; speedup vs baseline: 1.3861x; 1.3168x over previous
//
#include <hip/hip_runtime.h>

#define B_ 64
#define T_ 1024
#define J_ 52
#define CPB 4                       // chains (waves) per block
#define ROTF (J_ * 9)               // 468 floats per chain (local rotations)
#define CMPF (J_ * 16)              // 832 floats per chain (composed 4x4)
#define POSF (J_ * 3)               // 156 floats per chain (positions)
#define LDS_CMP (CPB * CMPF)        // 3328 floats = 13312 B
#define LDS_POS (CPB * POSF)        // 624 floats  =  2496 B

// Involutive XOR swizzle: byte bits [4:5] ^= bits [7:8].
// Bijective (upper-triangular over GF2), involution, keeps 16B alignment.
__device__ __forceinline__ int swz(int byte) {
    return byte ^ (((byte >> 7) & 3) << 4);
}

__global__ __launch_bounds__(256) void ForwardKinematics_38543036514646_kernel(
    const float* __restrict__ rotation,   // (B,T,J,3,3)
    const float* __restrict__ position,   // (B,T,3)
    const float* __restrict__ offsets,    // (B,J,3)
    const int*   __restrict__ parents,    // (J,)
    float* __restrict__ out_pos,          // (B,T,J,3)
    float* __restrict__ out_comp)         // (B,T,J,4,4)
{
    __shared__ float lds[LDS_CMP + LDS_POS];   // first 1872 floats reused for rot stage

    const int tid  = threadIdx.x;
    const int lane = tid & 63;
    const int wv   = tid >> 6;
    const long long bt0 = (long long)blockIdx.x * CPB;
    const long long bt  = bt0 + wv;
    const int b = (int)(bt >> 10);   // T = 1024

    // ---- stage CPB chains of rotations into LDS, fully coalesced float4 ----
    {
        const float4* src = (const float4*)(rotation + bt0 * ROTF);
        float4* dst = (float4*)lds;
        for (int i = tid; i < (CPB * ROTF) / 4; i += 256) dst[i] = src[i];
    }
    __syncthreads();

    const bool active = lane < J_;

    // ancestor pointer: virtual identity lane = 63 (self-loop)
    int anc = 63;
    if (lane > 0 && active) anc = parents[lane];

    // local transform -> running composed (identity for lanes >= J_, incl. 63)
    float a0=1.f,a1=0.f,a2=0.f,a3=0.f,a4=1.f,a5=0.f,a6=0.f,a7=0.f,a8=1.f;
    float t0=0.f,t1=0.f,t2=0.f;
    if (active) {
        const float* rp = lds + wv * ROTF + lane * 9;   // stride 9 dwords: conflict-free
        a0 = rp[0]; a1 = rp[1]; a2 = rp[2];
        a3 = rp[3]; a4 = rp[4]; a5 = rp[5];
        a6 = rp[6]; a7 = rp[7]; a8 = rp[8];
        if (lane == 0) {
            const float* pp = position + bt * 3;
            t0 = pp[0]; t1 = pp[1]; t2 = pp[2];
        } else {
            const float* op = offsets + ((long long)b * J_ + lane) * 3;
            t0 = op[0]; t1 = op[1]; t2 = op[2];
        }
    }
    __syncthreads();   // all rot LDS reads done; buffer will be overwritten below

    // exact wave-uniform trip count: min r with anc_r(j)==63 for all j
    int rounds = 0;
    {
        int aa = anc;
        while (rounds < 8 && !__all(aa == 63)) { aa = __shfl(aa, aa); ++rounds; }
    }

    // pointer-jumping, branch-free (composition with lane 63 is identity)
    #pragma unroll 1
    for (int r = 0; r < rounds; ++r) {
        float p0 = __shfl(a0, anc), p1 = __shfl(a1, anc), p2 = __shfl(a2, anc);
        float p3 = __shfl(a3, anc), p4 = __shfl(a4, anc), p5 = __shfl(a5, anc);
        float p6 = __shfl(a6, anc), p7 = __shfl(a7, anc), p8 = __shfl(a8, anc);
        float q0 = __shfl(t0, anc), q1 = __shfl(t1, anc), q2 = __shfl(t2, anc);
        int   na = __shfl(anc, anc);

        float n0 = p0*a0 + p1*a3 + p2*a6;
        float n1 = p0*a1 + p1*a4 + p2*a7;
        float n2 = p0*a2 + p1*a5 + p2*a8;
        float n3 = p3*a0 + p4*a3 + p5*a6;
        float n4 = p3*a1 + p4*a4 + p5*a7;
        float n5 = p3*a2 + p4*a5 + p5*a8;
        float n6 = p6*a0 + p7*a3 + p8*a6;
        float n7 = p6*a1 + p7*a4 + p8*a7;
        float n8 = p6*a2 + p7*a5 + p8*a8;
        float m0 = p0*t0 + p1*t1 + p2*t2 + q0;
        float m1 = p3*t0 + p4*t1 + p5*t2 + q1;
        float m2 = p6*t0 + p7*t1 + p8*t2 + q2;

        a0=n0; a1=n1; a2=n2; a3=n3; a4=n4; a5=n5; a6=n6; a7=n7; a8=n8;
        t0=m0; t1=m1; t2=m2;
        anc = na;
    }

    // ---- composed -> LDS (swizzled b128 writes), positions -> LDS ----
    if (active) {
        const int base = (wv * CMPF + lane * 16) * 4;   // byte offset in composed buf
        *(float4*)((char*)lds + swz(base +  0)) = make_float4(a0, a1, a2, t0);
        *(float4*)((char*)lds + swz(base + 16)) = make_float4(a3, a4, a5, t1);
        *(float4*)((char*)lds + swz(base + 32)) = make_float4(a6, a7, a8, t2);
        *(float4*)((char*)lds + swz(base + 48)) = make_float4(0.f, 0.f, 0.f, 1.f);
        float* lp = lds + LDS_CMP + wv * POSF + lane * 3;  // stride 3: conflict-free
        lp[0] = t0; lp[1] = t1; lp[2] = t2;
    }
    __syncthreads();

    // ---- stream both outputs out, fully contiguous float4 ----
    {
        float4* cd = (float4*)(out_comp + bt0 * CMPF);
        for (int i = tid; i < LDS_CMP / 4; i += 256) {
            cd[i] = *(const float4*)((const char*)lds + swz(i * 16));
        }
        float4* pd = (float4*)(out_pos + bt0 * POSF);
        const float4* ps4 = (const float4*)(lds + LDS_CMP);
        for (int i = tid; i < LDS_POS / 4; i += 256) pd[i] = ps4[i];
    }
}

extern "C" void kernel_launch(void* const* d_in, const int* in_sizes, int n_in,
                              void* d_out, int out_size, void* d_ws, size_t ws_size,
                              hipStream_t stream) {
    const float* rotation = (const float*)d_in[0];
    const float* position = (const float*)d_in[1];
    const float* offsets  = (const float*)d_in[2];
    const int*   parents  = (const int*)d_in[3];

    float* out_pos  = (float*)d_out;                                  // (B,T,J,3)
    float* out_comp = (float*)d_out + (size_t)B_ * T_ * J_ * 3;       // (B,T,J,4,4)

    dim3 block(256);                        // 4 waves = 4 chains per block
    dim3 grid((B_ * T_) / CPB);             // 16384 blocks
    hipLaunchKernelGGL(ForwardKinematics_38543036514646_kernel, grid, block, 0, stream,
                       rotation, position, offsets, parents, out_pos, out_comp);
}

// Round 5
// 69.751 us; speedup vs baseline: 1.4956x; 1.0790x over previous
//
#include <hip/hip_runtime.h>

#define B_ 64
#define T_ 1024
#define J_ 52
#define CPB 4                       // chains (waves) per block
#define ROTF (J_ * 9)               // 468 floats per chain (local rotations)
#define CMPF (J_ * 16)              // 832 floats per chain (composed 4x4)
#define POSF (J_ * 3)               // 156 floats per chain (positions)
#define LDS_CMP (CPB * CMPF)        // 3328 floats = 13312 B
#define LDS_POS (CPB * POSF)        // 624 floats  =  2496 B

typedef float f4 __attribute__((ext_vector_type(4)));   // nontemporal-builtin-compatible

// Involutive XOR swizzle: byte bits [4:5] ^= bits [7:8].
// Bijective, involution, keeps 16B alignment.
__device__ __forceinline__ int swz(int byte) {
    return byte ^ (((byte >> 7) & 3) << 4);
}

__global__ __launch_bounds__(256) void ForwardKinematics_38543036514646_kernel(
    const float* __restrict__ rotation,   // (B,T,J,3,3)
    const float* __restrict__ position,   // (B,T,3)
    const float* __restrict__ offsets,    // (B,J,3)
    const int*   __restrict__ parents,    // (J,)
    float* __restrict__ out_pos,          // (B,T,J,3)
    float* __restrict__ out_comp)         // (B,T,J,4,4)
{
    __shared__ float lds[LDS_CMP + LDS_POS];   // first 1872 floats reused for rot stage

    const int tid  = threadIdx.x;
    const int lane = tid & 63;
    const int wv   = tid >> 6;
    const long long bt0 = (long long)blockIdx.x * CPB;
    const long long bt  = bt0 + wv;
    const int b = (int)(bt >> 10);   // T = 1024

    // ---- stage CPB chains of rotations into LDS, coalesced nontemporal float4 ----
    {
        const f4* src = (const f4*)(rotation + bt0 * ROTF);
        f4* dst = (f4*)lds;
        for (int i = tid; i < (CPB * ROTF) / 4; i += 256)
            dst[i] = __builtin_nontemporal_load(src + i);
    }
    __syncthreads();

    const bool active = lane < J_;

    // ancestor pointer: virtual identity lane = 63 (self-loop)
    int anc = 63;
    if (lane > 0 && active) anc = parents[lane];

    // local transform -> running composed (identity for lanes >= J_, incl. 63)
    float a0=1.f,a1=0.f,a2=0.f,a3=0.f,a4=1.f,a5=0.f,a6=0.f,a7=0.f,a8=1.f;
    float t0=0.f,t1=0.f,t2=0.f;
    if (active) {
        const float* rp = lds + wv * ROTF + lane * 9;   // stride 9 dwords: conflict-free
        a0 = rp[0]; a1 = rp[1]; a2 = rp[2];
        a3 = rp[3]; a4 = rp[4]; a5 = rp[5];
        a6 = rp[6]; a7 = rp[7]; a8 = rp[8];
        if (lane == 0) {
            const float* pp = position + bt * 3;
            t0 = pp[0]; t1 = pp[1]; t2 = pp[2];
        } else {
            const float* op = offsets + ((long long)b * J_ + lane) * 3;
            t0 = op[0]; t1 = op[1]; t2 = op[2];
        }
    }
    __syncthreads();   // all rot LDS reads done; buffer will be overwritten below

    // exact wave-uniform trip count: min r with anc_r(j)==63 for all j
    int rounds = 0;
    {
        int aa = anc;
        while (rounds < 8 && !__all(aa == 63)) { aa = __shfl(aa, aa); ++rounds; }
    }

    // pointer-jumping, branch-free (composition with lane 63 is identity)
    #pragma unroll 1
    for (int r = 0; r < rounds; ++r) {
        float p0 = __shfl(a0, anc), p1 = __shfl(a1, anc), p2 = __shfl(a2, anc);
        float p3 = __shfl(a3, anc), p4 = __shfl(a4, anc), p5 = __shfl(a5, anc);
        float p6 = __shfl(a6, anc), p7 = __shfl(a7, anc), p8 = __shfl(a8, anc);
        float q0 = __shfl(t0, anc), q1 = __shfl(t1, anc), q2 = __shfl(t2, anc);
        int   na = __shfl(anc, anc);

        float n0 = p0*a0 + p1*a3 + p2*a6;
        float n1 = p0*a1 + p1*a4 + p2*a7;
        float n2 = p0*a2 + p1*a5 + p2*a8;
        float n3 = p3*a0 + p4*a3 + p5*a6;
        float n4 = p3*a1 + p4*a4 + p5*a7;
        float n5 = p3*a2 + p4*a5 + p5*a8;
        float n6 = p6*a0 + p7*a3 + p8*a6;
        float n7 = p6*a1 + p7*a4 + p8*a7;
        float n8 = p6*a2 + p7*a5 + p8*a8;
        float m0 = p0*t0 + p1*t1 + p2*t2 + q0;
        float m1 = p3*t0 + p4*t1 + p5*t2 + q1;
        float m2 = p6*t0 + p7*t1 + p8*t2 + q2;

        a0=n0; a1=n1; a2=n2; a3=n3; a4=n4; a5=n5; a6=n6; a7=n7; a8=n8;
        t0=m0; t1=m1; t2=m2;
        anc = na;
    }

    // ---- composed -> LDS (swizzled b128 writes), positions -> LDS ----
    if (active) {
        const int base = (wv * CMPF + lane * 16) * 4;   // byte offset in composed buf
        *(float4*)((char*)lds + swz(base +  0)) = make_float4(a0, a1, a2, t0);
        *(float4*)((char*)lds + swz(base + 16)) = make_float4(a3, a4, a5, t1);
        *(float4*)((char*)lds + swz(base + 32)) = make_float4(a6, a7, a8, t2);
        *(float4*)((char*)lds + swz(base + 48)) = make_float4(0.f, 0.f, 0.f, 1.f);
        float* lp = lds + LDS_CMP + wv * POSF + lane * 3;  // stride 3: conflict-free
        lp[0] = t0; lp[1] = t1; lp[2] = t2;
    }
    __syncthreads();

    // ---- stream both outputs out, contiguous nontemporal float4 ----
    {
        f4* cd = (f4*)(out_comp + bt0 * CMPF);
        for (int i = tid; i < LDS_CMP / 4; i += 256) {
            f4 v = *(const f4*)((const char*)lds + swz(i * 16));
            __builtin_nontemporal_store(v, cd + i);
        }
        f4* pd = (f4*)(out_pos + bt0 * POSF);
        const f4* ps4 = (const f4*)(lds + LDS_CMP);
        for (int i = tid; i < LDS_POS / 4; i += 256)
            __builtin_nontemporal_store(ps4[i], pd + i);
    }
}

extern "C" void kernel_launch(void* const* d_in, const int* in_sizes, int n_in,
                              void* d_out, int out_size, void* d_ws, size_t ws_size,
                              hipStream_t stream) {
    const float* rotation = (const float*)d_in[0];
    const float* position = (const float*)d_in[1];
    const float* offsets  = (const float*)d_in[2];
    const int*   parents  = (const int*)d_in[3];

    float* out_pos  = (float*)d_out;                                  // (B,T,J,3)
    float* out_comp = (float*)d_out + (size_t)B_ * T_ * J_ * 3;       // (B,T,J,4,4)

    dim3 block(256);                        // 4 waves = 4 chains per block
    dim3 grid((B_ * T_) / CPB);             // 16384 blocks
    hipLaunchKernelGGL(ForwardKinematics_38543036514646_kernel, grid, block, 0, stream,
                       rotation, position, offsets, parents, out_pos, out_comp);
}